// Round 12
// baseline (38.379 us; speedup 1.0000x reference)
//
#include <hip/hip_runtime.h>
#include <math.h>

#define EPS 1e-8f

constexpr int B = 32, N = 1024, M = 128, H = 2;

constexpr int ROWS_A   = 32;            // rows of L (and mem) per block
constexpr int CHUNKS_A = N / ROWS_A;    // 32
constexpr int NBLK_A   = B * CHUNKS_A;  // 1024
constexpr int ROWS_C   = 32;            // rows per k2 block
constexpr int CHUNKS_C = N / ROWS_C;    // 32

typedef float floatx4 __attribute__((ext_vector_type(4)));

// ---- K1: per block (b, chunk): f/bpart over 32 L-rows AND e over 32 mem-rows.
// ----     R7 structure (best: 37.3us) + nontemporal L loads (L is read-once;
// ----     keep it out of L2 so mem/bpart/e stay resident for k2).
// ----     R8: no min-waves clamp. R9/R10/R11: ILP/TLP variants all neutral.
__global__ __launch_bounds__(256) void k1(const float* __restrict__ L,
                                          const float* __restrict__ Wold,
                                          const float* __restrict__ mem,
                                          const float* __restrict__ keys,
                                          const float* __restrict__ strengths,
                                          const int* __restrict__ head,
                                          float* __restrict__ f,
                                          float* __restrict__ bpart,
                                          float* __restrict__ e,
                                          float* __restrict__ outMC) {
    int bid   = blockIdx.x;
    int t     = threadIdx.x;
    int lane  = t & 63, wave = t >> 6;
    int b     = bid / CHUNKS_A;
    int chunk = bid % CHUNKS_A;
    int r0    = chunk * ROWS_A;

    if (bid < 16) outMC[bid * 256 + t] = 0.f;   // B*M = 4096 = 16*256

    __shared__ float sw[N];
    __shared__ float lds_b[4][N];

    reinterpret_cast<float4*>(sw)[t] =
        reinterpret_cast<const float4*>(Wold + (size_t)b * N)[t];
    __syncthreads();

    float4 wreg[4];
    float4 bacc[4];
#pragma unroll
    for (int s = 0; s < 4; ++s) {
        wreg[s] = reinterpret_cast<float4*>(sw)[lane + 64 * s];
        bacc[s] = make_float4(0.f, 0.f, 0.f, 0.f);
    }

    const float* Lb = L + (size_t)b * N * N;
    for (int r = wave; r < ROWS_A; r += 4) {          // 8 rows per wave
        int i = r0 + r;
        const floatx4* row = reinterpret_cast<const floatx4*>(Lb + (size_t)i * N);
        float wi = sw[i];
        float pp = 0.f;
#pragma unroll
        for (int s = 0; s < 4; ++s) {
            floatx4 v = __builtin_nontemporal_load(row + lane + 64 * s);
            pp += v.x * wreg[s].x + v.y * wreg[s].y + v.z * wreg[s].z + v.w * wreg[s].w;
            bacc[s].x += v.x * wi;
            bacc[s].y += v.y * wi;
            bacc[s].z += v.z * wi;
            bacc[s].w += v.w * wi;
        }
#pragma unroll
        for (int off = 32; off; off >>= 1) pp += __shfl_down(pp, off, 64);
        if (lane == 0) f[(size_t)b * N + i] = pp;
    }

    // e-work: same 32 rows of memory (normal loads -> cache for k2 reuse)
    {
        int l32 = lane & 31, half = lane >> 5;
        int h   = head[0];
        float4 kv = reinterpret_cast<const float4*>(keys + ((size_t)b * H + h) * M)[l32];
        float  sk = kv.x * kv.x + kv.y * kv.y + kv.z * kv.z + kv.w * kv.w;
#pragma unroll
        for (int off = 16; off; off >>= 1) sk += __shfl_xor(sk, off, 64);
        float norm_k = sqrtf(sk);
        float beta   = strengths[(size_t)b * H + h];
#pragma unroll
        for (int rr = 0; rr < ROWS_A / 8; ++rr) {     // 4 iters, 2 rows/wave/iter
            int n = r0 + wave * 8 + rr * 2 + half;
            float4 mv = reinterpret_cast<const float4*>(mem + ((size_t)b * N + n) * M)[l32];
            float dot = mv.x * kv.x + mv.y * kv.y + mv.z * kv.z + mv.w * kv.w;
            float sm  = mv.x * mv.x + mv.y * mv.y + mv.z * mv.z + mv.w * mv.w;
#pragma unroll
            for (int off = 16; off; off >>= 1) {
                dot += __shfl_xor(dot, off, 64);
                sm  += __shfl_xor(sm, off, 64);
            }
            if (l32 == 0) {
                float denom = sqrtf(sm) * norm_k + EPS;
                e[(size_t)b * N + n] = expf(beta * dot / denom);
            }
        }
    }

#pragma unroll
    for (int s = 0; s < 4; ++s)
        reinterpret_cast<float4*>(lds_b[wave])[lane + 64 * s] = bacc[s];
    __syncthreads();

    float4 s0 = reinterpret_cast<float4*>(lds_b[0])[t];
    float4 s1 = reinterpret_cast<float4*>(lds_b[1])[t];
    float4 s2 = reinterpret_cast<float4*>(lds_b[2])[t];
    float4 s3 = reinterpret_cast<float4*>(lds_b[3])[t];
    float4 o;
    o.x = s0.x + s1.x + s2.x + s3.x;
    o.y = s0.y + s1.y + s2.y + s3.y;
    o.z = s0.z + s1.z + s2.z + s3.z;
    o.w = s0.w + s1.w + s2.w + s3.w;
    reinterpret_cast<float4*>(bpart + ((size_t)b * CHUNKS_A + chunk) * N)[t] = o;
}

// ---- K2: per 32-row chunk (1024 blocks -> 4/CU for latency hiding).
// ----     Redundant S = sum(e[b][:]) (4KB, cache-hot), bsum from bpart,
// ----     W -> outW directly, mc partial -> outMC via atomicAdd.
__global__ __launch_bounds__(256) void k2(const float* __restrict__ mem,
                                          const float* __restrict__ bpart,
                                          const float* __restrict__ f,
                                          const float* __restrict__ e,
                                          const float* __restrict__ mode,
                                          const int* __restrict__ head,
                                          float* __restrict__ outW,
                                          float* __restrict__ outMC) {
    int bid   = blockIdx.x;
    int b     = bid / CHUNKS_C;
    int chunk = bid % CHUNKS_C;
    int t     = threadIdx.x;
    int lane  = t & 63, wave = t >> 6;
    int r0    = chunk * ROWS_C;

    __shared__ float sred[4];
    __shared__ float bp[8][ROWS_C];
    __shared__ float swv[ROWS_C];
    __shared__ float4 lW[8][32];

    // phase 0: S = sum over e[b][:]
    float4 ev4 = reinterpret_cast<const float4*>(e + (size_t)b * N)[t];
    float es = ev4.x + ev4.y + ev4.z + ev4.w;
#pragma unroll
    for (int off = 32; off; off >>= 1) es += __shfl_down(es, off, 64);
    if (lane == 0) sred[wave] = es;

    // phase 1: bsum partials over CHUNKS_A, split across 8 c-groups
    int n_ = t & 31, cg_ = t >> 5;
    float s = 0.f;
#pragma unroll
    for (int c = cg_; c < CHUNKS_A; c += 8)
        s += bpart[((size_t)b * CHUNKS_A + c) * N + r0 + n_];
    __syncthreads();
    bp[cg_][n_] = s;
    __syncthreads();

    float S = sred[0] + sred[1] + sred[2] + sred[3];
    int h = head[0];
    const float* rm = mode + ((size_t)b * H + h) * 3;
    float coef = rm[1] / S;
    if (t < ROWS_C) {
        float bsum = bp[0][t] + bp[1][t] + bp[2][t] + bp[3][t]
                   + bp[4][t] + bp[5][t] + bp[6][t] + bp[7][t];
        float w = rm[0] * bsum + coef * e[(size_t)b * N + r0 + t]
                + rm[2] * f[(size_t)b * N + r0 + t];
        swv[t] = w;
        outW[(size_t)b * N + r0 + t] = w;
    }
    __syncthreads();

    // phase 2: fused mc partial over this chunk's 32 rows
    int cg = t & 31, rg = t >> 5;
    float4 aW = make_float4(0.f, 0.f, 0.f, 0.f);
#pragma unroll
    for (int rr = 0; rr < ROWS_C / 8; ++rr) {
        int r = rg + rr * 8;
        float4 v = reinterpret_cast<const float4*>(mem + ((size_t)b * N + r0 + r) * M)[cg];
        float ww = swv[r];
        aW.x += ww * v.x; aW.y += ww * v.y; aW.z += ww * v.z; aW.w += ww * v.w;
    }
    lW[rg][cg] = aW;
    __syncthreads();

    if (t < 32) {
        float4 oW = make_float4(0.f, 0.f, 0.f, 0.f);
#pragma unroll
        for (int g = 0; g < 8; ++g) {
            float4 vW = lW[g][t];
            oW.x += vW.x; oW.y += vW.y; oW.z += vW.z; oW.w += vW.w;
        }
        float* dst = outMC + (size_t)b * M + 4 * t;
        atomicAdd(dst + 0, oW.x);
        atomicAdd(dst + 1, oW.y);
        atomicAdd(dst + 2, oW.z);
        atomicAdd(dst + 3, oW.w);
    }
}

extern "C" void kernel_launch(void* const* d_in, const int* in_sizes, int n_in,
                              void* d_out, int out_size, void* d_ws, size_t ws_size,
                              hipStream_t stream) {
    const float* read_keys      = (const float*)d_in[0];
    const float* read_strengths = (const float*)d_in[1];
    const float* read_mode      = (const float*)d_in[2];
    const float* W_old          = (const float*)d_in[3];
    const float* L              = (const float*)d_in[4];
    const float* memory         = (const float*)d_in[5];
    const int*   head_no        = (const int*)d_in[6];

    float* out_W  = (float*)d_out;             // B*N
    float* out_mc = out_W + (size_t)B * N;     // B*M

    float* ws    = (float*)d_ws;
    float* f     = ws;                                    // B*N
    float* bpart = f + (size_t)B * N;                     // B*CHUNKS_A*N (4 MB)
    float* e     = bpart + (size_t)B * CHUNKS_A * N;      // B*N

    k1<<<NBLK_A, 256, 0, stream>>>(L, W_old, memory, read_keys,
                                   read_strengths, head_no, f, bpart, e, out_mc);
    k2<<<B * CHUNKS_C, 256, 0, stream>>>(memory, bpart, f, e, read_mode, head_no,
                                         out_W, out_mc);
}

// Round 13
// 37.028 us; speedup vs baseline: 1.0365x; 1.0365x over previous
//
#include <hip/hip_runtime.h>
#include <math.h>

#define EPS 1e-8f

constexpr int B = 32, N = 1024, M = 128, H = 2;

constexpr int ROWS_A   = 32;            // rows of L (and mem) per block
constexpr int CHUNKS_A = N / ROWS_A;    // 32
constexpr int NBLK_A   = B * CHUNKS_A;  // 1024
constexpr int ROWS_C   = 64;            // rows per k2 block
constexpr int CHUNKS_C = N / ROWS_C;    // 16

// ---- K1: R7 structure (best measured). Per block (b, chunk): f/bpart over
// ----     32 L-rows AND e over 32 mem-rows + per-chunk e-partial sum.
// ----     Lessons: R8 no min-waves clamp; R9/R10 no reduce restructure;
// ----     R11 no col-split; R12 no nontemporal.
__global__ __launch_bounds__(256) void k1(const float* __restrict__ L,
                                          const float* __restrict__ Wold,
                                          const float* __restrict__ mem,
                                          const float* __restrict__ keys,
                                          const float* __restrict__ strengths,
                                          const int* __restrict__ head,
                                          float* __restrict__ f,
                                          float* __restrict__ bpart,
                                          float* __restrict__ e,
                                          float* __restrict__ epart,
                                          float* __restrict__ outMC) {
    int bid   = blockIdx.x;
    int t     = threadIdx.x;
    int lane  = t & 63, wave = t >> 6;
    int b     = bid / CHUNKS_A;
    int chunk = bid % CHUNKS_A;
    int r0    = chunk * ROWS_A;

    if (bid < 16) outMC[bid * 256 + t] = 0.f;   // B*M = 4096 = 16*256

    __shared__ float sw[N];
    __shared__ float lds_b[4][N];
    __shared__ float lds_es[4];

    reinterpret_cast<float4*>(sw)[t] =
        reinterpret_cast<const float4*>(Wold + (size_t)b * N)[t];
    __syncthreads();

    float4 wreg[4];
    float4 bacc[4];
#pragma unroll
    for (int s = 0; s < 4; ++s) {
        wreg[s] = reinterpret_cast<float4*>(sw)[lane + 64 * s];
        bacc[s] = make_float4(0.f, 0.f, 0.f, 0.f);
    }

    const float* Lb = L + (size_t)b * N * N;
    for (int r = wave; r < ROWS_A; r += 4) {          // 8 rows per wave
        int i = r0 + r;
        const float4* row = reinterpret_cast<const float4*>(Lb + (size_t)i * N);
        float wi = sw[i];
        float pp = 0.f;
#pragma unroll
        for (int s = 0; s < 4; ++s) {
            float4 v = row[lane + 64 * s];
            pp += v.x * wreg[s].x + v.y * wreg[s].y + v.z * wreg[s].z + v.w * wreg[s].w;
            bacc[s].x += v.x * wi;
            bacc[s].y += v.y * wi;
            bacc[s].z += v.z * wi;
            bacc[s].w += v.w * wi;
        }
#pragma unroll
        for (int off = 32; off; off >>= 1) pp += __shfl_down(pp, off, 64);
        if (lane == 0) f[(size_t)b * N + i] = pp;
    }

    // e-work: same 32 rows of memory; also accumulate the chunk's e-sum
    float local_es = 0.f;
    {
        int l32 = lane & 31, half = lane >> 5;
        int h   = head[0];
        float4 kv = reinterpret_cast<const float4*>(keys + ((size_t)b * H + h) * M)[l32];
        float  sk = kv.x * kv.x + kv.y * kv.y + kv.z * kv.z + kv.w * kv.w;
#pragma unroll
        for (int off = 16; off; off >>= 1) sk += __shfl_xor(sk, off, 64);
        float norm_k = sqrtf(sk);
        float beta   = strengths[(size_t)b * H + h];
#pragma unroll
        for (int rr = 0; rr < ROWS_A / 8; ++rr) {     // 4 iters, 2 rows/wave/iter
            int n = r0 + wave * 8 + rr * 2 + half;
            float4 mv = reinterpret_cast<const float4*>(mem + ((size_t)b * N + n) * M)[l32];
            float dot = mv.x * kv.x + mv.y * kv.y + mv.z * kv.z + mv.w * kv.w;
            float sm  = mv.x * mv.x + mv.y * mv.y + mv.z * mv.z + mv.w * mv.w;
#pragma unroll
            for (int off = 16; off; off >>= 1) {
                dot += __shfl_xor(dot, off, 64);
                sm  += __shfl_xor(sm, off, 64);
            }
            if (l32 == 0) {
                float denom = sqrtf(sm) * norm_k + EPS;
                float ev = expf(beta * dot / denom);
                e[(size_t)b * N + n] = ev;
                local_es += ev;
            }
        }
        // wave e-sum (only lanes 0 and 32 hold nonzero)
#pragma unroll
        for (int off = 32; off; off >>= 1) local_es += __shfl_down(local_es, off, 64);
        if (lane == 0) lds_es[wave] = local_es;
    }

#pragma unroll
    for (int s = 0; s < 4; ++s)
        reinterpret_cast<float4*>(lds_b[wave])[lane + 64 * s] = bacc[s];
    __syncthreads();

    if (t == 0)
        epart[(size_t)b * CHUNKS_A + chunk] =
            lds_es[0] + lds_es[1] + lds_es[2] + lds_es[3];

    float4 s0 = reinterpret_cast<float4*>(lds_b[0])[t];
    float4 s1 = reinterpret_cast<float4*>(lds_b[1])[t];
    float4 s2 = reinterpret_cast<float4*>(lds_b[2])[t];
    float4 s3 = reinterpret_cast<float4*>(lds_b[3])[t];
    float4 o;
    o.x = s0.x + s1.x + s2.x + s3.x;
    o.y = s0.y + s1.y + s2.y + s3.y;
    o.z = s0.z + s1.z + s2.z + s3.z;
    o.w = s0.w + s1.w + s2.w + s3.w;
    reinterpret_cast<float4*>(bpart + ((size_t)b * CHUNKS_A + chunk) * N)[t] = o;
}

// ---- K2: per 64-row chunk. S from epart (32 scalars, not a 4KB e re-read),
// ----     bsum from bpart, W -> outW directly, mc partial -> outMC atomics.
__global__ __launch_bounds__(256) void k2(const float* __restrict__ mem,
                                          const float* __restrict__ bpart,
                                          const float* __restrict__ f,
                                          const float* __restrict__ e,
                                          const float* __restrict__ epart,
                                          const float* __restrict__ mode,
                                          const int* __restrict__ head,
                                          float* __restrict__ outW,
                                          float* __restrict__ outMC) {
    int bid   = blockIdx.x;
    int b     = bid / CHUNKS_C;
    int chunk = bid % CHUNKS_C;
    int t     = threadIdx.x;
    int r0    = chunk * ROWS_C;

    __shared__ float sS;
    __shared__ float bp[4][ROWS_C];
    __shared__ float swv[ROWS_C];
    __shared__ float4 lW[8][32];

    // phase 0: S = sum of 32 per-chunk e-partials (tiny, cache-hot)
    if (t < 64) {
        float es = (t < CHUNKS_A) ? epart[(size_t)b * CHUNKS_A + t] : 0.f;
#pragma unroll
        for (int off = 16; off; off >>= 1) es += __shfl_xor(es, off, 64);
        if (t == 0) sS = es;
    }

    // phase 1: bsum partials over CHUNKS_A, split across 4 c-groups
    int n_ = t & 63, cg_ = t >> 6;
    float s = 0.f;
#pragma unroll
    for (int c = cg_; c < CHUNKS_A; c += 4)
        s += bpart[((size_t)b * CHUNKS_A + c) * N + r0 + n_];
    bp[cg_][n_] = s;
    __syncthreads();

    float S = sS;
    int h = head[0];
    const float* rm = mode + ((size_t)b * H + h) * 3;
    float coef = rm[1] / S;
    if (t < ROWS_C) {
        float bsum = bp[0][t] + bp[1][t] + bp[2][t] + bp[3][t];
        float w = rm[0] * bsum + coef * e[(size_t)b * N + r0 + t]
                + rm[2] * f[(size_t)b * N + r0 + t];
        swv[t] = w;
        outW[(size_t)b * N + r0 + t] = w;
    }
    __syncthreads();

    // phase 2: fused mc partial over this chunk's 64 rows
    int cg = t & 31, rg = t >> 5;
    float4 aW = make_float4(0.f, 0.f, 0.f, 0.f);
#pragma unroll
    for (int rr = 0; rr < ROWS_C / 8; ++rr) {
        int r = rg + rr * 8;
        float4 v = reinterpret_cast<const float4*>(mem + ((size_t)b * N + r0 + r) * M)[cg];
        float ww = swv[r];
        aW.x += ww * v.x; aW.y += ww * v.y; aW.z += ww * v.z; aW.w += ww * v.w;
    }
    lW[rg][cg] = aW;
    __syncthreads();

    if (t < 32) {
        float4 oW = make_float4(0.f, 0.f, 0.f, 0.f);
#pragma unroll
        for (int g = 0; g < 8; ++g) {
            float4 vW = lW[g][t];
            oW.x += vW.x; oW.y += vW.y; oW.z += vW.z; oW.w += vW.w;
        }
        float* dst = outMC + (size_t)b * M + 4 * t;
        atomicAdd(dst + 0, oW.x);
        atomicAdd(dst + 1, oW.y);
        atomicAdd(dst + 2, oW.z);
        atomicAdd(dst + 3, oW.w);
    }
}

extern "C" void kernel_launch(void* const* d_in, const int* in_sizes, int n_in,
                              void* d_out, int out_size, void* d_ws, size_t ws_size,
                              hipStream_t stream) {
    const float* read_keys      = (const float*)d_in[0];
    const float* read_strengths = (const float*)d_in[1];
    const float* read_mode      = (const float*)d_in[2];
    const float* W_old          = (const float*)d_in[3];
    const float* L              = (const float*)d_in[4];
    const float* memory         = (const float*)d_in[5];
    const int*   head_no        = (const int*)d_in[6];

    float* out_W  = (float*)d_out;             // B*N
    float* out_mc = out_W + (size_t)B * N;     // B*M

    float* ws    = (float*)d_ws;
    float* f     = ws;                                    // B*N
    float* bpart = f + (size_t)B * N;                     // B*CHUNKS_A*N (4 MB)
    float* e     = bpart + (size_t)B * CHUNKS_A * N;      // B*N
    float* epart = e + (size_t)B * N;                     // B*CHUNKS_A

    k1<<<NBLK_A, 256, 0, stream>>>(L, W_old, memory, read_keys,
                                   read_strengths, head_no, f, bpart, e, epart, out_mc);
    k2<<<B * CHUNKS_C, 256, 0, stream>>>(memory, bpart, f, e, epart, read_mode,
                                         head_no, out_W, out_mc);
}

// Round 14
// 36.114 us; speedup vs baseline: 1.0627x; 1.0253x over previous
//
#include <hip/hip_runtime.h>
#include <math.h>

#define EPS 1e-8f

constexpr int B = 32, N = 1024, M = 128, H = 2;

constexpr int ROWS_A   = 64;            // rows of L (and mem) per block
constexpr int CHUNKS_A = N / ROWS_A;    // 16
constexpr int NBLK_A   = B * CHUNKS_A;  // 512
constexpr int ROWS_C   = 64;            // rows per k2 block
constexpr int CHUNKS_C = N / ROWS_C;    // 16

// ---- K1: R13 structure with ROWS_A=64 (amortization trend from R6->R7).
// ----     Per block (b, chunk): f/bpart over 64 L-rows AND e over 64 mem-rows
// ----     + per-chunk e-partial sum. Lessons: R8 no min-waves clamp;
// ----     R9/R10 no reduce restructure; R11 no col-split; R12 no nontemporal.
__global__ __launch_bounds__(256) void k1(const float* __restrict__ L,
                                          const float* __restrict__ Wold,
                                          const float* __restrict__ mem,
                                          const float* __restrict__ keys,
                                          const float* __restrict__ strengths,
                                          const int* __restrict__ head,
                                          float* __restrict__ f,
                                          float* __restrict__ bpart,
                                          float* __restrict__ e,
                                          float* __restrict__ epart,
                                          float* __restrict__ outMC) {
    int bid   = blockIdx.x;
    int t     = threadIdx.x;
    int lane  = t & 63, wave = t >> 6;
    int b     = bid / CHUNKS_A;
    int chunk = bid % CHUNKS_A;
    int r0    = chunk * ROWS_A;

    if (bid < 16) outMC[bid * 256 + t] = 0.f;   // B*M = 4096 = 16*256

    __shared__ float sw[N];
    __shared__ float lds_b[4][N];
    __shared__ float lds_es[4];

    reinterpret_cast<float4*>(sw)[t] =
        reinterpret_cast<const float4*>(Wold + (size_t)b * N)[t];
    __syncthreads();

    float4 wreg[4];
    float4 bacc[4];
#pragma unroll
    for (int s = 0; s < 4; ++s) {
        wreg[s] = reinterpret_cast<float4*>(sw)[lane + 64 * s];
        bacc[s] = make_float4(0.f, 0.f, 0.f, 0.f);
    }

    const float* Lb = L + (size_t)b * N * N;
    for (int r = wave; r < ROWS_A; r += 4) {          // 16 rows per wave
        int i = r0 + r;
        const float4* row = reinterpret_cast<const float4*>(Lb + (size_t)i * N);
        float wi = sw[i];
        float pp = 0.f;
#pragma unroll
        for (int s = 0; s < 4; ++s) {
            float4 v = row[lane + 64 * s];
            pp += v.x * wreg[s].x + v.y * wreg[s].y + v.z * wreg[s].z + v.w * wreg[s].w;
            bacc[s].x += v.x * wi;
            bacc[s].y += v.y * wi;
            bacc[s].z += v.z * wi;
            bacc[s].w += v.w * wi;
        }
#pragma unroll
        for (int off = 32; off; off >>= 1) pp += __shfl_down(pp, off, 64);
        if (lane == 0) f[(size_t)b * N + i] = pp;
    }

    // e-work: same 64 rows of memory; also accumulate the chunk's e-sum
    float local_es = 0.f;
    {
        int l32 = lane & 31, half = lane >> 5;
        int h   = head[0];
        float4 kv = reinterpret_cast<const float4*>(keys + ((size_t)b * H + h) * M)[l32];
        float  sk = kv.x * kv.x + kv.y * kv.y + kv.z * kv.z + kv.w * kv.w;
#pragma unroll
        for (int off = 16; off; off >>= 1) sk += __shfl_xor(sk, off, 64);
        float norm_k = sqrtf(sk);
        float beta   = strengths[(size_t)b * H + h];
#pragma unroll
        for (int rr = 0; rr < ROWS_A / 8; ++rr) {     // 8 iters, 2 rows/wave/iter
            int n = r0 + wave * 16 + rr * 2 + half;
            float4 mv = reinterpret_cast<const float4*>(mem + ((size_t)b * N + n) * M)[l32];
            float dot = mv.x * kv.x + mv.y * kv.y + mv.z * kv.z + mv.w * kv.w;
            float sm  = mv.x * mv.x + mv.y * mv.y + mv.z * mv.z + mv.w * mv.w;
#pragma unroll
            for (int off = 16; off; off >>= 1) {
                dot += __shfl_xor(dot, off, 64);
                sm  += __shfl_xor(sm, off, 64);
            }
            if (l32 == 0) {
                float denom = sqrtf(sm) * norm_k + EPS;
                float ev = expf(beta * dot / denom);
                e[(size_t)b * N + n] = ev;
                local_es += ev;
            }
        }
        // wave e-sum (only lanes 0 and 32 hold nonzero)
#pragma unroll
        for (int off = 32; off; off >>= 1) local_es += __shfl_down(local_es, off, 64);
        if (lane == 0) lds_es[wave] = local_es;
    }

#pragma unroll
    for (int s = 0; s < 4; ++s)
        reinterpret_cast<float4*>(lds_b[wave])[lane + 64 * s] = bacc[s];
    __syncthreads();

    if (t == 0)
        epart[(size_t)b * CHUNKS_A + chunk] =
            lds_es[0] + lds_es[1] + lds_es[2] + lds_es[3];

    float4 s0 = reinterpret_cast<float4*>(lds_b[0])[t];
    float4 s1 = reinterpret_cast<float4*>(lds_b[1])[t];
    float4 s2 = reinterpret_cast<float4*>(lds_b[2])[t];
    float4 s3 = reinterpret_cast<float4*>(lds_b[3])[t];
    float4 o;
    o.x = s0.x + s1.x + s2.x + s3.x;
    o.y = s0.y + s1.y + s2.y + s3.y;
    o.z = s0.z + s1.z + s2.z + s3.z;
    o.w = s0.w + s1.w + s2.w + s3.w;
    reinterpret_cast<float4*>(bpart + ((size_t)b * CHUNKS_A + chunk) * N)[t] = o;
}

// ---- K2: per 64-row chunk. S from epart (16 scalars), bsum from bpart,
// ----     W -> outW directly, mc partial -> outMC atomics.
__global__ __launch_bounds__(256) void k2(const float* __restrict__ mem,
                                          const float* __restrict__ bpart,
                                          const float* __restrict__ f,
                                          const float* __restrict__ e,
                                          const float* __restrict__ epart,
                                          const float* __restrict__ mode,
                                          const int* __restrict__ head,
                                          float* __restrict__ outW,
                                          float* __restrict__ outMC) {
    int bid   = blockIdx.x;
    int b     = bid / CHUNKS_C;
    int chunk = bid % CHUNKS_C;
    int t     = threadIdx.x;
    int r0    = chunk * ROWS_C;

    __shared__ float sS;
    __shared__ float bp[4][ROWS_C];
    __shared__ float swv[ROWS_C];
    __shared__ float4 lW[8][32];

    // phase 0: S = sum of 16 per-chunk e-partials (tiny, cache-hot)
    if (t < 64) {
        float es = (t < CHUNKS_A) ? epart[(size_t)b * CHUNKS_A + t] : 0.f;
#pragma unroll
        for (int off = 8; off; off >>= 1) es += __shfl_xor(es, off, 64);
        if (t == 0) sS = es;
    }

    // phase 1: bsum partials over CHUNKS_A, split across 4 c-groups
    int n_ = t & 63, cg_ = t >> 6;
    float s = 0.f;
#pragma unroll
    for (int c = cg_; c < CHUNKS_A; c += 4)
        s += bpart[((size_t)b * CHUNKS_A + c) * N + r0 + n_];
    bp[cg_][n_] = s;
    __syncthreads();

    float S = sS;
    int h = head[0];
    const float* rm = mode + ((size_t)b * H + h) * 3;
    float coef = rm[1] / S;
    if (t < ROWS_C) {
        float bsum = bp[0][t] + bp[1][t] + bp[2][t] + bp[3][t];
        float w = rm[0] * bsum + coef * e[(size_t)b * N + r0 + t]
                + rm[2] * f[(size_t)b * N + r0 + t];
        swv[t] = w;
        outW[(size_t)b * N + r0 + t] = w;
    }
    __syncthreads();

    // phase 2: fused mc partial over this chunk's 64 rows
    int cg = t & 31, rg = t >> 5;
    float4 aW = make_float4(0.f, 0.f, 0.f, 0.f);
#pragma unroll
    for (int rr = 0; rr < ROWS_C / 8; ++rr) {
        int r = rg + rr * 8;
        float4 v = reinterpret_cast<const float4*>(mem + ((size_t)b * N + r0 + r) * M)[cg];
        float ww = swv[r];
        aW.x += ww * v.x; aW.y += ww * v.y; aW.z += ww * v.z; aW.w += ww * v.w;
    }
    lW[rg][cg] = aW;
    __syncthreads();

    if (t < 32) {
        float4 oW = make_float4(0.f, 0.f, 0.f, 0.f);
#pragma unroll
        for (int g = 0; g < 8; ++g) {
            float4 vW = lW[g][t];
            oW.x += vW.x; oW.y += vW.y; oW.z += vW.z; oW.w += vW.w;
        }
        float* dst = outMC + (size_t)b * M + 4 * t;
        atomicAdd(dst + 0, oW.x);
        atomicAdd(dst + 1, oW.y);
        atomicAdd(dst + 2, oW.z);
        atomicAdd(dst + 3, oW.w);
    }
}

extern "C" void kernel_launch(void* const* d_in, const int* in_sizes, int n_in,
                              void* d_out, int out_size, void* d_ws, size_t ws_size,
                              hipStream_t stream) {
    const float* read_keys      = (const float*)d_in[0];
    const float* read_strengths = (const float*)d_in[1];
    const float* read_mode      = (const float*)d_in[2];
    const float* W_old          = (const float*)d_in[3];
    const float* L              = (const float*)d_in[4];
    const float* memory         = (const float*)d_in[5];
    const int*   head_no        = (const int*)d_in[6];

    float* out_W  = (float*)d_out;             // B*N
    float* out_mc = out_W + (size_t)B * N;     // B*M

    float* ws    = (float*)d_ws;
    float* f     = ws;                                    // B*N
    float* bpart = f + (size_t)B * N;                     // B*CHUNKS_A*N (2 MB)
    float* e     = bpart + (size_t)B * CHUNKS_A * N;      // B*N
    float* epart = e + (size_t)B * N;                     // B*CHUNKS_A

    k1<<<NBLK_A, 256, 0, stream>>>(L, W_old, memory, read_keys,
                                   read_strengths, head_no, f, bpart, e, epart, out_mc);
    k2<<<B * CHUNKS_C, 256, 0, stream>>>(memory, bpart, f, e, epart, read_mode,
                                         head_no, out_W, out_mc);
}